// Round 6
// baseline (358.755 us; speedup 1.0000x reference)
//
#include <hip/hip_runtime.h>
#include <stdint.h>

#define NH 16
#define SEQ 2048
#define HDIM 1024

typedef short bf16x8 __attribute__((ext_vector_type(8)));
typedef float f32x4 __attribute__((ext_vector_type(4)));

#define NEG_BIG (-1.0e30f)

// HW packed f32->bf16 convert (RNE), 1 instr per pair.
static __device__ __forceinline__ uint32_t cvtpk_bf16(float lo, float hi) {
  uint32_t r;
  asm("v_cvt_pk_bf16_f32 %0, %1, %2" : "=v"(r) : "v"(lo), "v"(hi));
  return r;
}
static __device__ __forceinline__ uint16_t f2bf(float f) {
  return (uint16_t)cvtpk_bf16(f, f);
}
// async global->LDS, 16B per lane; LDS dest = wave-uniform base + lane*16.
static __device__ __forceinline__ void gload_lds16(const void* g, void* l) {
  __builtin_amdgcn_global_load_lds(
      (const __attribute__((address_space(1))) void*)g,
      (__attribute__((address_space(3))) void*)l, 16, 0, 0);
}

// ---- f32 -> bf16 bulk convert (7 tensors in one launch) ----
struct CvtArgs {
  const float* src[7];
  uint16_t* dst[7];
  int nblk[7];   // blocks of 2048 elements
};
__global__ __launch_bounds__(256) void cvt_bf16(CvtArgs a) {
  int ten = blockIdx.y;
  if (blockIdx.x >= a.nblk[ten]) return;
  size_t idx = ((size_t)blockIdx.x * 256 + threadIdx.x) * 8;
  const float* s = a.src[ten] + idx;
  float4 f0 = *(const float4*)(s);
  float4 f1 = *(const float4*)(s + 4);
  uint4 o;
  o.x = cvtpk_bf16(f0.x, f0.y);
  o.y = cvtpk_bf16(f0.z, f0.w);
  o.z = cvtpk_bf16(f1.x, f1.y);
  o.w = cvtpk_bf16(f1.z, f1.w);
  *(uint4*)(a.dst[ten] + idx) = o;
}

// cm[b,q,k] = mask ? sm * (log2e/8) : -1.0   (bf16); sm is f32, mask int32
__global__ __launch_bounds__(256) void cm_prep(const int4* __restrict__ mask,
                                               const float4* __restrict__ sm,
                                               uint4* __restrict__ cm) {
  int i = blockIdx.x * 256 + threadIdx.x;   // one group of 8 elements
  int4 m0 = mask[2 * i];
  int4 m1 = mask[2 * i + 1];
  float4 s0 = sm[2 * i];
  float4 s1 = sm[2 * i + 1];
  const float cst = 0.18033688011112042f;  // log2(e)/8
  auto pk = [&](int mA, int mB, float fa, float fb) -> uint32_t {
    float a = mA ? fa * cst : -1.0f;
    float b = mB ? fb * cst : -1.0f;
    return cvtpk_bf16(a, b);
  };
  uint4 o;
  o.x = pk(m0.x, m0.y, s0.x, s0.y);
  o.y = pk(m0.z, m0.w, s0.z, s0.w);
  o.z = pk(m1.x, m1.y, s1.x, s1.y);
  o.w = pk(m1.z, m1.w, s1.z, s1.w);
  cm[i] = o;
}

struct GemmArgs {
  const uint16_t* A[4];
  const uint16_t* B[4];
  const float* bias[4];
  void* C[4];
};

// C = A @ B^T (+bias), A [M,1024] bf16 K-major, B [N,1024] bf16 K-major.
// 3-buffer LDS rotation, global_load_lds, counted vmcnt, 1 barrier/K-step.
// Used for QKV (modes 0..2), grid 768 = 3 blocks/CU.
__global__ __launch_bounds__(256) void gemm_bt(GemmArgs ga, int modeBase) {
  int mode = modeBase + blockIdx.y;
  const uint16_t* __restrict__ A = ga.A[mode];
  const uint16_t* __restrict__ Bm = ga.B[mode];
  const float* __restrict__ bias = ga.bias[mode];

  int bid = blockIdx.x;
  int tm, tn;
  if (mode == 2) { tm = bid & 7; tn = bid >> 3; }   // M=1024, N=4096
  else           { tm = bid >> 3; tn = bid & 7; }   // M=4096, N=1024

  __shared__ uint16_t As[3][128 * 32];   // 3 x 8 KB, linear (gload_lds dest)
  __shared__ uint16_t Bs[3][128 * 32];

  int t = threadIdx.x;
  int lane = t & 63, w = t >> 6;
  int quad = lane >> 4, lm = lane & 15;
  int wm = w >> 1, wn = w & 1;

  const uint16_t* Ab = A + (size_t)tm * 128 * 1024;
  const uint16_t* Bb = Bm + (size_t)tn * 128 * 1024;

  int srow = lane >> 2;
  int scol = (lane & 3) * 8;
  const uint16_t* gA0 = Ab + (size_t)(w * 32 + srow) * 1024 + scol;
  const uint16_t* gA1 = gA0 + 16 * 1024;
  const uint16_t* gB0 = Bb + (size_t)(w * 32 + srow) * 1024 + scol;
  const uint16_t* gB1 = gB0 + 16 * 1024;

  uint16_t* rdA = As[0]; uint16_t* stA = As[1]; uint16_t* nxA = As[2];
  uint16_t* rdB = Bs[0]; uint16_t* stB = Bs[1]; uint16_t* nxB = Bs[2];
  int woff = w * 1024;   // wave's 32-row block within a buffer (elems)

  auto STAGE = [&](uint16_t* dA, uint16_t* dB) {
    gload_lds16(gA0, dA + woff);
    gload_lds16(gA1, dA + woff + 512);
    gload_lds16(gB0, dB + woff);
    gload_lds16(gB1, dB + woff + 512);
    gA0 += 32; gA1 += 32; gB0 += 32; gB1 += 32;
  };

  f32x4 acc[4][4] = {};

  STAGE(rdA, rdB);   // prologue: K-step 0 into buf0

  for (int kk = 0; kk < 1024; kk += 32) {
    if (kk + 32 < 1024) {
      STAGE(stA, stB);   // issue next K-step loads; complete under MFMA below
      asm volatile("s_waitcnt vmcnt(4)" ::: "memory");  // rd-buf staged
    } else {
      asm volatile("s_waitcnt vmcnt(0)" ::: "memory");
    }
    __builtin_amdgcn_s_barrier();            // all waves' rd-buf staged
    __builtin_amdgcn_sched_barrier(0);       // pin ds_reads below barrier

    bf16x8 af[4], bfr[4];
#pragma unroll
    for (int i = 0; i < 4; i++)
      af[i] = *(const bf16x8*)&rdA[(wm * 64 + i * 16 + lm) * 32 + quad * 8];
#pragma unroll
    for (int j = 0; j < 4; j++)
      bfr[j] = *(const bf16x8*)&rdB[(wn * 64 + j * 16 + lm) * 32 + quad * 8];
#pragma unroll
    for (int i = 0; i < 4; i++)
#pragma unroll
      for (int j = 0; j < 4; j++)
        acc[i][j] = __builtin_amdgcn_mfma_f32_16x16x32_bf16(af[i], bfr[j], acc[i][j], 0, 0, 0);

    uint16_t* tA = rdA; rdA = stA; stA = nxA; nxA = tA;
    uint16_t* tB = rdB; rdB = stB; stB = nxB; nxB = tB;
  }

  int rowb = tm * 128 + wm * 64;
  int colb = tn * 128 + wn * 64;
#pragma unroll
  for (int i = 0; i < 4; i++) {
#pragma unroll
    for (int j = 0; j < 4; j++) {
      int col = colb + j * 16 + lm;
#pragma unroll
      for (int r = 0; r < 4; r++) {
        int row = rowb + i * 16 + quad * 4 + r;
        float v = acc[i][j][r];
        if (mode == 2) {
          v += bias[row];
          int hh = row >> 6, hd = row & 63, b = col >> 11, s2 = col & 2047;
          ((uint16_t*)ga.C[2])[((size_t)((b * NH + hh) * 64 + hd) << 11) + s2] = f2bf(v);
        } else {
          v += bias[col];
          int b = row >> 11, s2 = row & 2047, hh = col >> 6, hd = col & 63;
          ((uint16_t*)ga.C[mode])[(((size_t)(b * NH + hh) * 2048 + s2) << 6) + hd] = f2bf(v);
        }
      }
    }
  }
}

// Out-projection: C[4096,1024] f32 = A[4096,1024]bf16 @ B[1024,1024]^T + bo.
// BM=64 x BN=128 tiles -> 512 blocks = 2 blocks/CU (grid-limited occupancy
// doubled vs the 256-block 128x128 version). 3-buffer pipeline, 36 KB LDS.
__global__ __launch_bounds__(256) void gemm_out(const uint16_t* __restrict__ A,
                                                const uint16_t* __restrict__ Bm,
                                                const float* __restrict__ bias,
                                                float* __restrict__ C) {
  int bid = blockIdx.x;
  int tm = bid >> 3;     // 64 M-tiles
  int tn = bid & 7;      // 8 N-tiles

  __shared__ uint16_t As[3][64 * 32];    // 3 x 4 KB
  __shared__ uint16_t Bs[3][128 * 32];   // 3 x 8 KB

  int t = threadIdx.x;
  int lane = t & 63, w = t >> 6;
  int quad = lane >> 4, lm = lane & 15;
  int wm = w >> 1, wn = w & 1;

  const uint16_t* Ab = A + (size_t)tm * 64 * 1024;
  const uint16_t* Bb = Bm + (size_t)tn * 128 * 1024;

  int srow = lane >> 2;
  int scol = (lane & 3) * 8;
  const uint16_t* gA0 = Ab + (size_t)(w * 16 + srow) * 1024 + scol;   // A: 16 rows/wave
  const uint16_t* gB0 = Bb + (size_t)(w * 32 + srow) * 1024 + scol;   // B: 32 rows/wave
  const uint16_t* gB1 = gB0 + 16 * 1024;

  uint16_t* rdA = As[0]; uint16_t* stA = As[1]; uint16_t* nxA = As[2];
  uint16_t* rdB = Bs[0]; uint16_t* stB = Bs[1]; uint16_t* nxB = Bs[2];
  int woffA = w * 512;    // 16 rows * 32
  int woffB = w * 1024;   // 32 rows * 32

  auto STAGE = [&](uint16_t* dA, uint16_t* dB) {
    gload_lds16(gA0, dA + woffA);
    gload_lds16(gB0, dB + woffB);
    gload_lds16(gB1, dB + woffB + 512);
    gA0 += 32; gB0 += 32; gB1 += 32;
  };

  f32x4 acc[2][4] = {};

  STAGE(rdA, rdB);

  for (int kk = 0; kk < 1024; kk += 32) {
    if (kk + 32 < 1024) {
      STAGE(stA, stB);
      asm volatile("s_waitcnt vmcnt(3)" ::: "memory");
    } else {
      asm volatile("s_waitcnt vmcnt(0)" ::: "memory");
    }
    __builtin_amdgcn_s_barrier();
    __builtin_amdgcn_sched_barrier(0);

    bf16x8 af[2], bfr[4];
#pragma unroll
    for (int i = 0; i < 2; i++)
      af[i] = *(const bf16x8*)&rdA[(wm * 32 + i * 16 + lm) * 32 + quad * 8];
#pragma unroll
    for (int j = 0; j < 4; j++)
      bfr[j] = *(const bf16x8*)&rdB[(wn * 64 + j * 16 + lm) * 32 + quad * 8];
#pragma unroll
    for (int i = 0; i < 2; i++)
#pragma unroll
      for (int j = 0; j < 4; j++)
        acc[i][j] = __builtin_amdgcn_mfma_f32_16x16x32_bf16(af[i], bfr[j], acc[i][j], 0, 0, 0);

    uint16_t* tA = rdA; rdA = stA; stA = nxA; nxA = tA;
    uint16_t* tB = rdB; rdB = stB; stB = nxB; nxB = tB;
  }

  int rowb = tm * 64 + wm * 32;
  int colb = tn * 128 + wn * 64;
#pragma unroll
  for (int i = 0; i < 2; i++) {
#pragma unroll
    for (int j = 0; j < 4; j++) {
      int col = colb + j * 16 + lm;
      float bv = bias[col];
#pragma unroll
      for (int r = 0; r < 4; r++) {
        int row = rowb + i * 16 + quad * 4 + r;
        C[(size_t)row * 1024 + col] = acc[i][j][r] + bv;
      }
    }
  }
}

#define LDK 72  // 64x64 tile rows padded to 72 elems (144B, 16B-aligned)
#define KVBUF (64 * LDK)

// Flash attention. One WG = (head, 64-row q tile, batch). 4 waves, 256 thr.
// Double-buffered K/V LDS: ONE barrier per tile; tile t+1 global loads issue
// at tile-t top (T14 issue-early/write-late), regs -> LDS[X^1] at tile end.
__global__ __launch_bounds__(256) void attn(const uint16_t* __restrict__ qp,
                                            const uint16_t* __restrict__ kp,
                                            const uint16_t* __restrict__ vt,
                                            const uint16_t* __restrict__ cm,
                                            uint16_t* __restrict__ ao) {
  int h = blockIdx.x, qt = blockIdx.y, b = blockIdx.z;
  int t = threadIdx.x;
  int lane = t & 63, w = t >> 6;
  int quad = lane >> 4, c = lane & 15;

  __shared__ uint16_t Ks[2 * KVBUF];    // [X][k][hd]
  __shared__ uint16_t VTs[2 * KVBUF];   // [X][hd][k]
  __shared__ uint16_t Ps[KVBUF];        // [q][k] (wave-private rows)

  size_t bh = (size_t)(b * NH + h);
  const uint16_t* Kb = kp + bh * (SEQ * 64);
  const uint16_t* Vb = vt + bh * (64 * SEQ);
  const uint16_t* CMb = cm + ((size_t)b * SEQ + qt * 64) * SEQ;

  int qrow = qt * 64 + w * 16 + c;
  const uint16_t* Qb = qp + bh * (SEQ * 64) + (size_t)qrow * 64;
  bf16x8 qf0 = *(const bf16x8*)(Qb + quad * 8);        // B-frag: Q[q][hd 0..32)
  bf16x8 qf1 = *(const bf16x8*)(Qb + 32 + quad * 8);   // hd 32..64

  f32x4 Oacc[4] = {};
  float m_run = NEG_BIG;
  float l_run = 0.0f;

  int krow = w * 8 + (lane >> 3);    // rows krow, krow+32
  int kc = (lane & 7) * 8;           // 16B chunk

  const uint16_t* pK0 = Kb + (size_t)krow * 64 + kc;
  const uint16_t* pK1 = pK0 + 32 * 64;
  const uint16_t* pV0 = Vb + (size_t)krow * SEQ + kc;
  const uint16_t* pV1 = pV0 + (size_t)32 * SEQ;
  const uint16_t* pCM = CMb + (size_t)(w * 16 + c) * SEQ + quad * 4;

  uint16_t* sK0 = &Ks[krow * LDK + kc];
  uint16_t* sK1 = sK0 + 32 * LDK;
  uint16_t* sV0 = &VTs[krow * LDK + kc];
  uint16_t* sV1 = sV0 + 32 * LDK;

  const uint16_t* rK = &Ks[c * LDK];
  const uint16_t* rV = &VTs[c * LDK];
  uint16_t* sP = &Ps[(w * 16 + c) * LDK];
  int qo = quad * 8;

  // --- prologue: stage tile 0 into buffer 0 ---
  {
    uint4 k0  = *(const uint4*)(pK0);
    uint4 k1  = *(const uint4*)(pK1);
    uint4 v0g = *(const uint4*)(pV0);
    uint4 v1g = *(const uint4*)(pV1);
    pK0 += 64 * 64; pK1 += 64 * 64; pV0 += 64; pV1 += 64;
    *(uint4*)sK0 = k0;
    *(uint4*)sK1 = k1;
    *(uint4*)sV0 = v0g;
    *(uint4*)sV1 = v1g;
    asm volatile("s_waitcnt lgkmcnt(0)" ::: "memory");
    __builtin_amdgcn_s_barrier();
  }

  int X = 0;
  for (int kt = 0; kt < SEQ; kt += 64) {
    // CM for current tile (L3-resident; covered by the QK phase)
    uint2 cm0 = *(const uint2*)(pCM);
    uint2 cm1 = *(const uint2*)(pCM + 16);
    uint2 cm2 = *(const uint2*)(pCM + 32);
    uint2 cm3 = *(const uint2*)(pCM + 48);
    pCM += 64;
    // issue NEXT tile's K/V loads now: full-tile latency cover
    bool more = (kt + 64 < SEQ);
    uint4 k0, k1, v0g, v1g;
    if (more) {
      k0  = *(const uint4*)(pK0);
      k1  = *(const uint4*)(pK1);
      v0g = *(const uint4*)(pV0);
      v1g = *(const uint4*)(pV1);
      pK0 += 64 * 64; pK1 += 64 * 64; pV0 += 64; pV1 += 64;
    }

    const uint16_t* rKX = rK + X * KVBUF;
    const uint16_t* rVX = rV + X * KVBUF;

    f32x4 st[4];
    __builtin_amdgcn_s_setprio(1);
#pragma unroll
    for (int i = 0; i < 4; i++) {
      bf16x8 a0 = *(const bf16x8*)(rKX + i * 16 * LDK + qo);
      bf16x8 a1 = *(const bf16x8*)(rKX + i * 16 * LDK + 32 + qo);
      f32x4 z = {};
      z = __builtin_amdgcn_mfma_f32_16x16x32_bf16(a0, qf0, z, 0, 0, 0);
      st[i] = __builtin_amdgcn_mfma_f32_16x16x32_bf16(a1, qf1, z, 0, 0, 0);
    }
    __builtin_amdgcn_s_setprio(0);

    float p[16];
    float tmax = NEG_BIG;
    uint2 cmv[4] = {cm0, cm1, cm2, cm3};
#pragma unroll
    for (int i = 0; i < 4; i++) {
      uint32_t w0 = cmv[i].x, w1 = cmv[i].y;
      float cf[4];
      cf[0] = __builtin_bit_cast(float, w0 << 16);
      cf[1] = __builtin_bit_cast(float, w0 & 0xffff0000u);
      cf[2] = __builtin_bit_cast(float, w1 << 16);
      cf[3] = __builtin_bit_cast(float, w1 & 0xffff0000u);
#pragma unroll
      for (int r = 0; r < 4; r++) {
        float sv = st[i][r] * cf[r];
        sv = (cf[r] < 0.0f) ? NEG_BIG : sv;   // mask==0 -> -inf
        p[i * 4 + r] = sv;
      }
      tmax = fmaxf(tmax,
                   fmaxf(fmaxf(p[i * 4 + 0], p[i * 4 + 1]),
                         fmaxf(p[i * 4 + 2], p[i * 4 + 3])));
    }
    tmax = fmaxf(tmax, __shfl_xor(tmax, 16));
    tmax = fmaxf(tmax, __shfl_xor(tmax, 32));
    // T13 defer-max: skip rescale unless max grew by >8 (p bounded by 2^8)
    if (!__all(tmax <= m_run + 8.0f)) {
      float m_new = fmaxf(m_run, tmax);
      float alpha = exp2f(m_run - m_new);
      m_run = m_new;
      l_run *= alpha;
#pragma unroll
      for (int i = 0; i < 4; i++) Oacc[i] *= alpha;
    }
    float ls = 0.0f;
#pragma unroll
    for (int z2 = 0; z2 < 16; z2++) {
      p[z2] = exp2f(p[z2] - m_run);
      ls += p[z2];
    }
    l_run += ls;

#pragma unroll
    for (int i = 0; i < 4; i++) {
      uint2 pkd;
      pkd.x = cvtpk_bf16(p[i * 4 + 0], p[i * 4 + 1]);
      pkd.y = cvtpk_bf16(p[i * 4 + 2], p[i * 4 + 3]);
      *(uint2*)(sP + i * 16 + quad * 4) = pkd;
    }
    // P rows are wave-private: wave-local DS drain instead of __syncthreads
    asm volatile("s_waitcnt lgkmcnt(0)" ::: "memory");
    __builtin_amdgcn_sched_barrier(0);

    bf16x8 pf0 = *(const bf16x8*)(sP + qo);
    bf16x8 pf1 = *(const bf16x8*)(sP + 32 + qo);
    __builtin_amdgcn_s_setprio(1);
#pragma unroll
    for (int i = 0; i < 4; i++) {
      bf16x8 v0 = *(const bf16x8*)(rVX + i * 16 * LDK + qo);
      bf16x8 v1 = *(const bf16x8*)(rVX + i * 16 * LDK + 32 + qo);
      Oacc[i] = __builtin_amdgcn_mfma_f32_16x16x32_bf16(v0, pf0, Oacc[i], 0, 0, 0);
      Oacc[i] = __builtin_amdgcn_mfma_f32_16x16x32_bf16(v1, pf1, Oacc[i], 0, 0, 0);
    }
    __builtin_amdgcn_s_setprio(0);

    if (more) {
      // write next tile into the other buffer; everyone finished reading it
      // one barrier ago. Single barrier per tile.
      int Y = X ^ 1;
      *(uint4*)(sK0 + Y * KVBUF) = k0;
      *(uint4*)(sK1 + Y * KVBUF) = k1;
      *(uint4*)(sV0 + Y * KVBUF) = v0g;
      *(uint4*)(sV1 + Y * KVBUF) = v1g;
      asm volatile("s_waitcnt lgkmcnt(0)" ::: "memory");
      __builtin_amdgcn_s_barrier();
      X = Y;
    }
  }

  float lf = l_run + __shfl_xor(l_run, 16);
  lf = lf + __shfl_xor(lf, 32);
  float inv = 1.0f / lf;
  uint16_t* Ob = ao + ((size_t)(b * SEQ) + qt * 64 + w * 16 + c) * HDIM + h * 64;
#pragma unroll
  for (int i = 0; i < 4; i++) {
    uint2 ov;
    ov.x = cvtpk_bf16(Oacc[i][0] * inv, Oacc[i][1] * inv);
    ov.y = cvtpk_bf16(Oacc[i][2] * inv, Oacc[i][3] * inv);
    *(uint2*)(Ob + i * 16 + quad * 4) = ov;
  }
}

extern "C" void kernel_launch(void* const* d_in, const int* in_sizes, int n_in,
                              void* d_out, int out_size, void* d_ws, size_t ws_size,
                              hipStream_t stream) {
  (void)in_sizes; (void)n_in; (void)out_size; (void)ws_size;
  const float* query = (const float*)d_in[0];
  const float* key   = (const float*)d_in[1];
  const float* value = (const float*)d_in[2];
  const int*   mask  = (const int*)d_in[3];
  const float* smask = (const float*)d_in[4];
  const float* Wq = (const float*)d_in[5];
  const float* bq = (const float*)d_in[6];
  const float* Wk = (const float*)d_in[7];
  const float* bk = (const float*)d_in[8];
  const float* Wv = (const float*)d_in[9];
  const float* bv = (const float*)d_in[10];
  const float* Wo = (const float*)d_in[11];
  const float* bo = (const float*)d_in[12];

  char* p = (char*)d_ws;
  uint16_t* xq  = (uint16_t*)p; p += (size_t)2 * SEQ * HDIM * 2;       // 8 MB
  uint16_t* xk  = (uint16_t*)p; p += (size_t)2 * SEQ * HDIM * 2;       // 8 MB
  uint16_t* xv  = (uint16_t*)p; p += (size_t)2 * SEQ * HDIM * 2;       // 8 MB
  uint16_t* wqb = (uint16_t*)p; p += (size_t)HDIM * HDIM * 2;          // 2 MB
  uint16_t* wkb = (uint16_t*)p; p += (size_t)HDIM * HDIM * 2;          // 2 MB
  uint16_t* wvb = (uint16_t*)p; p += (size_t)HDIM * HDIM * 2;          // 2 MB
  uint16_t* wob = (uint16_t*)p; p += (size_t)HDIM * HDIM * 2;          // 2 MB
  uint16_t* qp  = (uint16_t*)p; p += (size_t)2 * NH * SEQ * 64 * 2;    // 8 MB
  uint16_t* kpp = (uint16_t*)p; p += (size_t)2 * NH * SEQ * 64 * 2;    // 8 MB
  uint16_t* vtp = (uint16_t*)p; p += (size_t)2 * NH * SEQ * 64 * 2;    // 8 MB
  uint16_t* cmw = (uint16_t*)p; p += (size_t)2 * SEQ * SEQ * 2;        // 16 MB
  uint16_t* aob = (uint16_t*)p; p += (size_t)2 * SEQ * HDIM * 2;       // 8 MB

  CvtArgs ca;
  ca.src[0] = query; ca.dst[0] = xq;  ca.nblk[0] = 2048;   // 4M elems
  ca.src[1] = key;   ca.dst[1] = xk;  ca.nblk[1] = 2048;
  ca.src[2] = value; ca.dst[2] = xv;  ca.nblk[2] = 2048;
  ca.src[3] = Wq;    ca.dst[3] = wqb; ca.nblk[3] = 512;    // 1M elems
  ca.src[4] = Wk;    ca.dst[4] = wkb; ca.nblk[4] = 512;
  ca.src[5] = Wv;    ca.dst[5] = wvb; ca.nblk[5] = 512;
  ca.src[6] = Wo;    ca.dst[6] = wob; ca.nblk[6] = 512;
  cvt_bf16<<<dim3(2048, 7), 256, 0, stream>>>(ca);

  cm_prep<<<4096, 256, 0, stream>>>((const int4*)mask, (const float4*)smask, (uint4*)cmw);

  GemmArgs ga;
  ga.A[0] = xq;  ga.B[0] = wqb; ga.bias[0] = bq; ga.C[0] = qp;
  ga.A[1] = xk;  ga.B[1] = wkb; ga.bias[1] = bk; ga.C[1] = kpp;
  ga.A[2] = wvb; ga.B[2] = xv;  ga.bias[2] = bv; ga.C[2] = vtp;
  ga.A[3] = aob; ga.B[3] = wob; ga.bias[3] = bo; ga.C[3] = d_out;

  gemm_bt<<<dim3(256, 3), 256, 0, stream>>>(ga, 0);                // fused QKV
  attn<<<dim3(NH, SEQ / 64, 2), 256, 0, stream>>>(qp, kpp, vtp, cmw, aob);
  gemm_out<<<512, 256, 0, stream>>>(aob, wob, bo, (float*)d_out);  // output proj
}

// Round 7
// 330.630 us; speedup vs baseline: 1.0851x; 1.0851x over previous
//
#include <hip/hip_runtime.h>
#include <stdint.h>

#define NH 16
#define SEQ 2048
#define HDIM 1024

typedef short bf16x8 __attribute__((ext_vector_type(8)));
typedef float f32x4 __attribute__((ext_vector_type(4)));

#define NEG_BIG (-1.0e30f)

// HW packed f32->bf16 convert (RNE), 1 instr per pair.
static __device__ __forceinline__ uint32_t cvtpk_bf16(float lo, float hi) {
  uint32_t r;
  asm("v_cvt_pk_bf16_f32 %0, %1, %2" : "=v"(r) : "v"(lo), "v"(hi));
  return r;
}
static __device__ __forceinline__ uint16_t f2bf(float f) {
  return (uint16_t)cvtpk_bf16(f, f);
}
// async global->LDS, 16B per lane; LDS dest = wave-uniform base + lane*16.
static __device__ __forceinline__ void gload_lds16(const void* g, void* l) {
  __builtin_amdgcn_global_load_lds(
      (const __attribute__((address_space(1))) void*)g,
      (__attribute__((address_space(3))) void*)l, 16, 0, 0);
}

// ---- merged prep: f32->bf16 cvt (7 tensors) + cm build, one launch ----
// blocks 0..6143   : cvt q/k/v      (ten = x>>11, blk = x&2047, 2048 each)
// blocks 6144..8191: cvt weights    (ten = 3 + (y>>9), blk = y&511, 512 each)
// blocks 8192..12287: cm_prep       (4096 blocks)
struct PrepArgs {
  const float* src[7];
  uint16_t* dst[7];
  const int4* mask;
  const float4* sm;
  uint4* cmw;
};
__global__ __launch_bounds__(256) void prep(PrepArgs a) {
  int x = blockIdx.x;
  if (x < 8192) {
    int ten, blk;
    if (x < 6144) { ten = x >> 11; blk = x & 2047; }
    else          { int y = x - 6144; ten = 3 + (y >> 9); blk = y & 511; }
    size_t idx = ((size_t)blk * 256 + threadIdx.x) * 8;
    const float* s = a.src[ten] + idx;
    float4 f0 = *(const float4*)(s);
    float4 f1 = *(const float4*)(s + 4);
    uint4 o;
    o.x = cvtpk_bf16(f0.x, f0.y);
    o.y = cvtpk_bf16(f0.z, f0.w);
    o.z = cvtpk_bf16(f1.x, f1.y);
    o.w = cvtpk_bf16(f1.z, f1.w);
    *(uint4*)(a.dst[ten] + idx) = o;
  } else {
    int i = (x - 8192) * 256 + threadIdx.x;   // one group of 8 elements
    int4 m0 = a.mask[2 * i];
    int4 m1 = a.mask[2 * i + 1];
    float4 s0 = a.sm[2 * i];
    float4 s1 = a.sm[2 * i + 1];
    const float cst = 0.18033688011112042f;  // log2(e)/8
    auto pk = [&](int mA, int mB, float fa, float fb) -> uint32_t {
      float va = mA ? fa * cst : -1.0f;
      float vb = mB ? fb * cst : -1.0f;
      return cvtpk_bf16(va, vb);
    };
    uint4 o;
    o.x = pk(m0.x, m0.y, s0.x, s0.y);
    o.y = pk(m0.z, m0.w, s0.z, s0.w);
    o.z = pk(m1.x, m1.y, s1.x, s1.y);
    o.w = pk(m1.z, m1.w, s1.z, s1.w);
    a.cmw[i] = o;
  }
}

struct GemmArgs {
  const uint16_t* A[4];
  const uint16_t* B[4];
  const float* bias[4];
  void* C[4];
};

// C = A @ B^T (+bias), A [M,1024] bf16 K-major, B [N,1024] bf16 K-major.
// 3-buffer LDS rotation, global_load_lds, counted vmcnt, 1 barrier/K-step.
// Used for QKV (modes 0..2), grid 768 = 3 blocks/CU.
__global__ __launch_bounds__(256) void gemm_bt(GemmArgs ga, int modeBase) {
  int mode = modeBase + blockIdx.y;
  const uint16_t* __restrict__ A = ga.A[mode];
  const uint16_t* __restrict__ Bm = ga.B[mode];
  const float* __restrict__ bias = ga.bias[mode];

  int bid = blockIdx.x;
  int tm, tn;
  if (mode == 2) { tm = bid & 7; tn = bid >> 3; }   // M=1024, N=4096
  else           { tm = bid >> 3; tn = bid & 7; }   // M=4096, N=1024

  __shared__ uint16_t As[3][128 * 32];   // 3 x 8 KB, linear (gload_lds dest)
  __shared__ uint16_t Bs[3][128 * 32];

  int t = threadIdx.x;
  int lane = t & 63, w = t >> 6;
  int quad = lane >> 4, lm = lane & 15;
  int wm = w >> 1, wn = w & 1;

  const uint16_t* Ab = A + (size_t)tm * 128 * 1024;
  const uint16_t* Bb = Bm + (size_t)tn * 128 * 1024;

  int srow = lane >> 2;
  int scol = (lane & 3) * 8;
  const uint16_t* gA0 = Ab + (size_t)(w * 32 + srow) * 1024 + scol;
  const uint16_t* gA1 = gA0 + 16 * 1024;
  const uint16_t* gB0 = Bb + (size_t)(w * 32 + srow) * 1024 + scol;
  const uint16_t* gB1 = gB0 + 16 * 1024;

  uint16_t* rdA = As[0]; uint16_t* stA = As[1]; uint16_t* nxA = As[2];
  uint16_t* rdB = Bs[0]; uint16_t* stB = Bs[1]; uint16_t* nxB = Bs[2];
  int woff = w * 1024;   // wave's 32-row block within a buffer (elems)

  auto STAGE = [&](uint16_t* dA, uint16_t* dB) {
    gload_lds16(gA0, dA + woff);
    gload_lds16(gA1, dA + woff + 512);
    gload_lds16(gB0, dB + woff);
    gload_lds16(gB1, dB + woff + 512);
    gA0 += 32; gA1 += 32; gB0 += 32; gB1 += 32;
  };

  f32x4 acc[4][4] = {};

  STAGE(rdA, rdB);   // prologue: K-step 0 into buf0

  for (int kk = 0; kk < 1024; kk += 32) {
    if (kk + 32 < 1024) {
      STAGE(stA, stB);   // issue next K-step loads; complete under MFMA below
      asm volatile("s_waitcnt vmcnt(4)" ::: "memory");  // rd-buf staged
    } else {
      asm volatile("s_waitcnt vmcnt(0)" ::: "memory");
    }
    __builtin_amdgcn_s_barrier();            // all waves' rd-buf staged
    __builtin_amdgcn_sched_barrier(0);       // pin ds_reads below barrier

    bf16x8 af[4], bfr[4];
#pragma unroll
    for (int i = 0; i < 4; i++)
      af[i] = *(const bf16x8*)&rdA[(wm * 64 + i * 16 + lm) * 32 + quad * 8];
#pragma unroll
    for (int j = 0; j < 4; j++)
      bfr[j] = *(const bf16x8*)&rdB[(wn * 64 + j * 16 + lm) * 32 + quad * 8];
#pragma unroll
    for (int i = 0; i < 4; i++)
#pragma unroll
      for (int j = 0; j < 4; j++)
        acc[i][j] = __builtin_amdgcn_mfma_f32_16x16x32_bf16(af[i], bfr[j], acc[i][j], 0, 0, 0);

    uint16_t* tA = rdA; rdA = stA; stA = nxA; nxA = tA;
    uint16_t* tB = rdB; rdB = stB; stB = nxB; nxB = tB;
  }

  int rowb = tm * 128 + wm * 64;
  int colb = tn * 128 + wn * 64;
#pragma unroll
  for (int i = 0; i < 4; i++) {
#pragma unroll
    for (int j = 0; j < 4; j++) {
      int col = colb + j * 16 + lm;
#pragma unroll
      for (int r = 0; r < 4; r++) {
        int row = rowb + i * 16 + quad * 4 + r;
        float v = acc[i][j][r];
        if (mode == 2) {
          v += bias[row];
          int hh = row >> 6, hd = row & 63, b = col >> 11, s2 = col & 2047;
          ((uint16_t*)ga.C[2])[((size_t)((b * NH + hh) * 64 + hd) << 11) + s2] = f2bf(v);
        } else {
          v += bias[col];
          int b = row >> 11, s2 = row & 2047, hh = col >> 6, hd = col & 63;
          ((uint16_t*)ga.C[mode])[(((size_t)(b * NH + hh) * 2048 + s2) << 6) + hd] = f2bf(v);
        }
      }
    }
  }
}

// Out-projection: C[4096,1024] f32 = A[4096,1024]bf16 @ B[1024,1024]^T + bo.
// BM=64 x BN=128 tiles -> 512 blocks = 2 blocks/CU. 3-buffer pipeline.
__global__ __launch_bounds__(256) void gemm_out(const uint16_t* __restrict__ A,
                                                const uint16_t* __restrict__ Bm,
                                                const float* __restrict__ bias,
                                                float* __restrict__ C) {
  int bid = blockIdx.x;
  int tm = bid >> 3;     // 64 M-tiles
  int tn = bid & 7;      // 8 N-tiles

  __shared__ uint16_t As[3][64 * 32];    // 3 x 4 KB
  __shared__ uint16_t Bs[3][128 * 32];   // 3 x 8 KB

  int t = threadIdx.x;
  int lane = t & 63, w = t >> 6;
  int quad = lane >> 4, lm = lane & 15;
  int wm = w >> 1, wn = w & 1;

  const uint16_t* Ab = A + (size_t)tm * 64 * 1024;
  const uint16_t* Bb = Bm + (size_t)tn * 128 * 1024;

  int srow = lane >> 2;
  int scol = (lane & 3) * 8;
  const uint16_t* gA0 = Ab + (size_t)(w * 16 + srow) * 1024 + scol;   // A: 16 rows/wave
  const uint16_t* gB0 = Bb + (size_t)(w * 32 + srow) * 1024 + scol;   // B: 32 rows/wave
  const uint16_t* gB1 = gB0 + 16 * 1024;

  uint16_t* rdA = As[0]; uint16_t* stA = As[1]; uint16_t* nxA = As[2];
  uint16_t* rdB = Bs[0]; uint16_t* stB = Bs[1]; uint16_t* nxB = Bs[2];
  int woffA = w * 512;    // 16 rows * 32
  int woffB = w * 1024;   // 32 rows * 32

  auto STAGE = [&](uint16_t* dA, uint16_t* dB) {
    gload_lds16(gA0, dA + woffA);
    gload_lds16(gB0, dB + woffB);
    gload_lds16(gB1, dB + woffB + 512);
    gA0 += 32; gB0 += 32; gB1 += 32;
  };

  f32x4 acc[2][4] = {};

  STAGE(rdA, rdB);

  for (int kk = 0; kk < 1024; kk += 32) {
    if (kk + 32 < 1024) {
      STAGE(stA, stB);
      asm volatile("s_waitcnt vmcnt(3)" ::: "memory");
    } else {
      asm volatile("s_waitcnt vmcnt(0)" ::: "memory");
    }
    __builtin_amdgcn_s_barrier();
    __builtin_amdgcn_sched_barrier(0);

    bf16x8 af[2], bfr[4];
#pragma unroll
    for (int i = 0; i < 2; i++)
      af[i] = *(const bf16x8*)&rdA[(wm * 32 + i * 16 + lm) * 32 + quad * 8];
#pragma unroll
    for (int j = 0; j < 4; j++)
      bfr[j] = *(const bf16x8*)&rdB[(wn * 64 + j * 16 + lm) * 32 + quad * 8];
#pragma unroll
    for (int i = 0; i < 2; i++)
#pragma unroll
      for (int j = 0; j < 4; j++)
        acc[i][j] = __builtin_amdgcn_mfma_f32_16x16x32_bf16(af[i], bfr[j], acc[i][j], 0, 0, 0);

    uint16_t* tA = rdA; rdA = stA; stA = nxA; nxA = tA;
    uint16_t* tB = rdB; rdB = stB; stB = nxB; nxB = tB;
  }

  int rowb = tm * 64 + wm * 32;
  int colb = tn * 128 + wn * 64;
#pragma unroll
  for (int i = 0; i < 2; i++) {
#pragma unroll
    for (int j = 0; j < 4; j++) {
      int col = colb + j * 16 + lm;
      float bv = bias[col];
#pragma unroll
      for (int r = 0; r < 4; r++) {
        int row = rowb + i * 16 + quad * 4 + r;
        C[(size_t)row * 1024 + col] = acc[i][j][r] + bv;
      }
    }
  }
}

#define LDK 72  // 64x64 tile rows padded to 72 elems (144B, 16B-aligned)

// Flash attention. One WG = (head, 64-row q tile, batch). 4 waves, 256 thr.
// R5 structure (verified 106.7us): CM direct from global, wave-private P rows,
// simple 2-barrier tile loop -- inter-WG TLP covers the latency; every
// pipelining restructure (R2, R6) regressed. FROZEN.
__global__ __launch_bounds__(256) void attn(const uint16_t* __restrict__ qp,
                                            const uint16_t* __restrict__ kp,
                                            const uint16_t* __restrict__ vt,
                                            const uint16_t* __restrict__ cm,
                                            uint16_t* __restrict__ ao) {
  int h = blockIdx.x, qt = blockIdx.y, b = blockIdx.z;
  int t = threadIdx.x;
  int lane = t & 63, w = t >> 6;
  int quad = lane >> 4, c = lane & 15;

  __shared__ uint16_t Ks[64 * LDK];    // [k][hd]
  __shared__ uint16_t VTs[64 * LDK];   // [hd][k]
  __shared__ uint16_t Ps[64 * LDK];    // [q][k] (wave-private rows)

  size_t bh = (size_t)(b * NH + h);
  const uint16_t* Kb = kp + bh * (SEQ * 64);
  const uint16_t* Vb = vt + bh * (64 * SEQ);
  const uint16_t* CMb = cm + ((size_t)b * SEQ + qt * 64) * SEQ;

  int qrow = qt * 64 + w * 16 + c;
  const uint16_t* Qb = qp + bh * (SEQ * 64) + (size_t)qrow * 64;
  bf16x8 qf0 = *(const bf16x8*)(Qb + quad * 8);        // B-frag: Q[q][hd 0..32)
  bf16x8 qf1 = *(const bf16x8*)(Qb + 32 + quad * 8);   // hd 32..64

  f32x4 Oacc[4] = {};
  float m_run = NEG_BIG;
  float l_run = 0.0f;

  int krow = w * 8 + (lane >> 3);    // rows krow, krow+32
  int kc = (lane & 7) * 8;           // 16B chunk

  const uint16_t* pK0 = Kb + (size_t)krow * 64 + kc;
  const uint16_t* pK1 = pK0 + 32 * 64;
  const uint16_t* pV0 = Vb + (size_t)krow * SEQ + kc;
  const uint16_t* pV1 = pV0 + (size_t)32 * SEQ;
  const uint16_t* pCM = CMb + (size_t)(w * 16 + c) * SEQ + quad * 4;

  uint16_t* sK0 = &Ks[krow * LDK + kc];
  uint16_t* sK1 = sK0 + 32 * LDK;
  uint16_t* sV0 = &VTs[krow * LDK + kc];
  uint16_t* sV1 = sV0 + 32 * LDK;

  const uint16_t* rK = &Ks[c * LDK];
  const uint16_t* rV = &VTs[c * LDK];
  uint16_t* sP = &Ps[(w * 16 + c) * LDK];
  int qo = quad * 8;

  for (int kt = 0; kt < SEQ; kt += 64) {
    uint2 cm0 = *(const uint2*)(pCM);
    uint2 cm1 = *(const uint2*)(pCM + 16);
    uint2 cm2 = *(const uint2*)(pCM + 32);
    uint2 cm3 = *(const uint2*)(pCM + 48);
    uint4 k0  = *(const uint4*)(pK0);
    uint4 k1  = *(const uint4*)(pK1);
    uint4 v0g = *(const uint4*)(pV0);
    uint4 v1g = *(const uint4*)(pV1);
    pCM += 64; pK0 += 64 * 64; pK1 += 64 * 64; pV0 += 64; pV1 += 64;
    __syncthreads();                 // prev-tile LDS reads done
    *(uint4*)sK0 = k0;
    *(uint4*)sK1 = k1;
    *(uint4*)sV0 = v0g;
    *(uint4*)sV1 = v1g;
    __syncthreads();                 // tile staged

    f32x4 st[4];
    __builtin_amdgcn_s_setprio(1);
#pragma unroll
    for (int i = 0; i < 4; i++) {
      bf16x8 a0 = *(const bf16x8*)(rK + i * 16 * LDK + qo);
      bf16x8 a1 = *(const bf16x8*)(rK + i * 16 * LDK + 32 + qo);
      f32x4 z = {};
      z = __builtin_amdgcn_mfma_f32_16x16x32_bf16(a0, qf0, z, 0, 0, 0);
      st[i] = __builtin_amdgcn_mfma_f32_16x16x32_bf16(a1, qf1, z, 0, 0, 0);
    }
    __builtin_amdgcn_s_setprio(0);

    float p[16];
    float tmax = NEG_BIG;
    uint2 cmv[4] = {cm0, cm1, cm2, cm3};
#pragma unroll
    for (int i = 0; i < 4; i++) {
      uint32_t w0 = cmv[i].x, w1 = cmv[i].y;
      float cf[4];
      cf[0] = __builtin_bit_cast(float, w0 << 16);
      cf[1] = __builtin_bit_cast(float, w0 & 0xffff0000u);
      cf[2] = __builtin_bit_cast(float, w1 << 16);
      cf[3] = __builtin_bit_cast(float, w1 & 0xffff0000u);
#pragma unroll
      for (int r = 0; r < 4; r++) {
        float sv = st[i][r] * cf[r];
        sv = (cf[r] < 0.0f) ? NEG_BIG : sv;   // mask==0 -> -inf
        p[i * 4 + r] = sv;
      }
      tmax = fmaxf(tmax,
                   fmaxf(fmaxf(p[i * 4 + 0], p[i * 4 + 1]),
                         fmaxf(p[i * 4 + 2], p[i * 4 + 3])));
    }
    tmax = fmaxf(tmax, __shfl_xor(tmax, 16));
    tmax = fmaxf(tmax, __shfl_xor(tmax, 32));
    // T13 defer-max: skip rescale unless max grew by >8 (p bounded by 2^8)
    if (!__all(tmax <= m_run + 8.0f)) {
      float m_new = fmaxf(m_run, tmax);
      float alpha = exp2f(m_run - m_new);
      m_run = m_new;
      l_run *= alpha;
#pragma unroll
      for (int i = 0; i < 4; i++) Oacc[i] *= alpha;
    }
    float ls = 0.0f;
#pragma unroll
    for (int z2 = 0; z2 < 16; z2++) {
      p[z2] = exp2f(p[z2] - m_run);
      ls += p[z2];
    }
    l_run += ls;

#pragma unroll
    for (int i = 0; i < 4; i++) {
      uint2 pkd;
      pkd.x = cvtpk_bf16(p[i * 4 + 0], p[i * 4 + 1]);
      pkd.y = cvtpk_bf16(p[i * 4 + 2], p[i * 4 + 3]);
      *(uint2*)(sP + i * 16 + quad * 4) = pkd;
    }
    // P rows are wave-private: wave-local DS drain instead of __syncthreads
    asm volatile("s_waitcnt lgkmcnt(0)" ::: "memory");
    __builtin_amdgcn_sched_barrier(0);

    bf16x8 pf0 = *(const bf16x8*)(sP + qo);
    bf16x8 pf1 = *(const bf16x8*)(sP + 32 + qo);
    __builtin_amdgcn_s_setprio(1);
#pragma unroll
    for (int i = 0; i < 4; i++) {
      bf16x8 v0 = *(const bf16x8*)(rV + i * 16 * LDK + qo);
      bf16x8 v1 = *(const bf16x8*)(rV + i * 16 * LDK + 32 + qo);
      Oacc[i] = __builtin_amdgcn_mfma_f32_16x16x32_bf16(v0, pf0, Oacc[i], 0, 0, 0);
      Oacc[i] = __builtin_amdgcn_mfma_f32_16x16x32_bf16(v1, pf1, Oacc[i], 0, 0, 0);
    }
    __builtin_amdgcn_s_setprio(0);
  }

  float lf = l_run + __shfl_xor(l_run, 16);
  lf = lf + __shfl_xor(lf, 32);
  float inv = 1.0f / lf;
  uint16_t* Ob = ao + ((size_t)(b * SEQ) + qt * 64 + w * 16 + c) * HDIM + h * 64;
#pragma unroll
  for (int i = 0; i < 4; i++) {
    uint2 ov;
    ov.x = cvtpk_bf16(Oacc[i][0] * inv, Oacc[i][1] * inv);
    ov.y = cvtpk_bf16(Oacc[i][2] * inv, Oacc[i][3] * inv);
    *(uint2*)(Ob + i * 16 + quad * 4) = ov;
  }
}

extern "C" void kernel_launch(void* const* d_in, const int* in_sizes, int n_in,
                              void* d_out, int out_size, void* d_ws, size_t ws_size,
                              hipStream_t stream) {
  (void)in_sizes; (void)n_in; (void)out_size; (void)ws_size;
  const float* query = (const float*)d_in[0];
  const float* key   = (const float*)d_in[1];
  const float* value = (const float*)d_in[2];
  const int*   mask  = (const int*)d_in[3];
  const float* smask = (const float*)d_in[4];
  const float* Wq = (const float*)d_in[5];
  const float* bq = (const float*)d_in[6];
  const float* Wk = (const float*)d_in[7];
  const float* bk = (const float*)d_in[8];
  const float* Wv = (const float*)d_in[9];
  const float* bv = (const float*)d_in[10];
  const float* Wo = (const float*)d_in[11];
  const float* bo = (const float*)d_in[12];

  char* p = (char*)d_ws;
  uint16_t* xq  = (uint16_t*)p; p += (size_t)2 * SEQ * HDIM * 2;       // 8 MB
  uint16_t* xk  = (uint16_t*)p; p += (size_t)2 * SEQ * HDIM * 2;       // 8 MB
  uint16_t* xv  = (uint16_t*)p; p += (size_t)2 * SEQ * HDIM * 2;       // 8 MB
  uint16_t* wqb = (uint16_t*)p; p += (size_t)HDIM * HDIM * 2;          // 2 MB
  uint16_t* wkb = (uint16_t*)p; p += (size_t)HDIM * HDIM * 2;          // 2 MB
  uint16_t* wvb = (uint16_t*)p; p += (size_t)HDIM * HDIM * 2;          // 2 MB
  uint16_t* wob = (uint16_t*)p; p += (size_t)HDIM * HDIM * 2;          // 2 MB
  uint16_t* qp  = (uint16_t*)p; p += (size_t)2 * NH * SEQ * 64 * 2;    // 8 MB
  uint16_t* kpp = (uint16_t*)p; p += (size_t)2 * NH * SEQ * 64 * 2;    // 8 MB
  uint16_t* vtp = (uint16_t*)p; p += (size_t)2 * NH * SEQ * 64 * 2;    // 8 MB
  uint16_t* cmw = (uint16_t*)p; p += (size_t)2 * SEQ * SEQ * 2;        // 16 MB
  uint16_t* aob = (uint16_t*)p; p += (size_t)2 * SEQ * HDIM * 2;       // 8 MB

  PrepArgs pa;
  pa.src[0] = query; pa.dst[0] = xq;
  pa.src[1] = key;   pa.dst[1] = xk;
  pa.src[2] = value; pa.dst[2] = xv;
  pa.src[3] = Wq;    pa.dst[3] = wqb;
  pa.src[4] = Wk;    pa.dst[4] = wkb;
  pa.src[5] = Wv;    pa.dst[5] = wvb;
  pa.src[6] = Wo;    pa.dst[6] = wob;
  pa.mask = (const int4*)mask;
  pa.sm   = (const float4*)smask;
  pa.cmw  = (uint4*)cmw;
  prep<<<12288, 256, 0, stream>>>(pa);

  GemmArgs ga;
  ga.A[0] = xq;  ga.B[0] = wqb; ga.bias[0] = bq; ga.C[0] = qp;
  ga.A[1] = xk;  ga.B[1] = wkb; ga.bias[1] = bk; ga.C[1] = kpp;
  ga.A[2] = wvb; ga.B[2] = xv;  ga.bias[2] = bv; ga.C[2] = vtp;
  ga.A[3] = aob; ga.B[3] = wob; ga.bias[3] = bo; ga.C[3] = d_out;

  gemm_bt<<<dim3(256, 3), 256, 0, stream>>>(ga, 0);                // fused QKV
  attn<<<dim3(NH, SEQ / 64, 2), 256, 0, stream>>>(qp, kpp, vtp, cmw, aob);
  gemm_out<<<512, 256, 0, stream>>>(aob, wob, bo, (float*)d_out);  // output proj
}

// Round 9
// 329.779 us; speedup vs baseline: 1.0879x; 1.0026x over previous
//
#include <hip/hip_runtime.h>
#include <stdint.h>

#define NH 16
#define SEQ 2048
#define HDIM 1024

typedef short bf16x8 __attribute__((ext_vector_type(8)));
typedef float f32x4 __attribute__((ext_vector_type(4)));

#define NEG_BIG (-1.0e30f)

// HW packed f32->bf16 convert (RNE), 1 instr per pair.
static __device__ __forceinline__ uint32_t cvtpk_bf16(float lo, float hi) {
  uint32_t r;
  asm("v_cvt_pk_bf16_f32 %0, %1, %2" : "=v"(r) : "v"(lo), "v"(hi));
  return r;
}
static __device__ __forceinline__ uint16_t f2bf(float f) {
  return (uint16_t)cvtpk_bf16(f, f);
}
// async global->LDS, 16B per lane; LDS dest = wave-uniform base + lane*16.
static __device__ __forceinline__ void gload_lds16(const void* g, void* l) {
  __builtin_amdgcn_global_load_lds(
      (const __attribute__((address_space(1))) void*)g,
      (__attribute__((address_space(3))) void*)l, 16, 0, 0);
}

// ---- merged prep: f32->bf16 cvt (7 tensors) + cm build, one launch ----
struct PrepArgs {
  const float* src[7];
  uint16_t* dst[7];
  const int4* mask;
  const float4* sm;
  uint4* cmw;
};
__global__ __launch_bounds__(256) void prep(PrepArgs a) {
  int x = blockIdx.x;
  if (x < 8192) {
    int ten, blk;
    if (x < 6144) { ten = x >> 11; blk = x & 2047; }
    else          { int y = x - 6144; ten = 3 + (y >> 9); blk = y & 511; }
    size_t idx = ((size_t)blk * 256 + threadIdx.x) * 8;
    const float* s = a.src[ten] + idx;
    float4 f0 = *(const float4*)(s);
    float4 f1 = *(const float4*)(s + 4);
    uint4 o;
    o.x = cvtpk_bf16(f0.x, f0.y);
    o.y = cvtpk_bf16(f0.z, f0.w);
    o.z = cvtpk_bf16(f1.x, f1.y);
    o.w = cvtpk_bf16(f1.z, f1.w);
    *(uint4*)(a.dst[ten] + idx) = o;
  } else {
    int i = (x - 8192) * 256 + threadIdx.x;   // one group of 8 elements
    int4 m0 = a.mask[2 * i];
    int4 m1 = a.mask[2 * i + 1];
    float4 s0 = a.sm[2 * i];
    float4 s1 = a.sm[2 * i + 1];
    const float cst = 0.18033688011112042f;  // log2(e)/8
    auto pk = [&](int mA, int mB, float fa, float fb) -> uint32_t {
      float va = mA ? fa * cst : -1.0f;
      float vb = mB ? fb * cst : -1.0f;
      return cvtpk_bf16(va, vb);
    };
    uint4 o;
    o.x = pk(m0.x, m0.y, s0.x, s0.y);
    o.y = pk(m0.z, m0.w, s0.z, s0.w);
    o.z = pk(m1.x, m1.y, s1.x, s1.y);
    o.w = pk(m1.z, m1.w, s1.z, s1.w);
    a.cmw[i] = o;
  }
}

struct GemmArgs {
  const uint16_t* A[4];
  const uint16_t* B[4];
  const float* bias[4];
  void* C[4];
};

// C = A @ B^T (+bias), A [M,1024] bf16 K-major, B [N,1024] bf16 K-major.
// Depth-2 prefetch on 3 LDS buffers. Per step: vmcnt(4) drains THIS wave's
// step-i stage (issued at i-2); s_barrier then proves ALL waves' step-i data
// landed (each drained before rendezvous -- cross-wave safe); STAGE(i+2)
// after the barrier targets the buffer read at i-1 (reads completed before
// the barrier -> no WAR).
__global__ __launch_bounds__(256) void gemm_bt(GemmArgs ga, int modeBase) {
  int mode = modeBase + blockIdx.y;
  const uint16_t* __restrict__ A = ga.A[mode];
  const uint16_t* __restrict__ Bm = ga.B[mode];
  const float* __restrict__ bias = ga.bias[mode];

  int bid = blockIdx.x;
  int tm, tn;
  if (mode == 2) { tm = bid & 7; tn = bid >> 3; }   // M=1024, N=4096
  else           { tm = bid >> 3; tn = bid & 7; }   // M=4096, N=1024

  __shared__ uint16_t As[3][128 * 32];   // 3 x 8 KB, linear (gload_lds dest)
  __shared__ uint16_t Bs[3][128 * 32];

  int t = threadIdx.x;
  int lane = t & 63, w = t >> 6;
  int quad = lane >> 4, lm = lane & 15;
  int wm = w >> 1, wn = w & 1;

  const uint16_t* Ab = A + (size_t)tm * 128 * 1024;
  const uint16_t* Bb = Bm + (size_t)tn * 128 * 1024;

  int srow = lane >> 2;
  int scol = (lane & 3) * 8;
  const uint16_t* gA0 = Ab + (size_t)(w * 32 + srow) * 1024 + scol;
  const uint16_t* gA1 = gA0 + 16 * 1024;
  const uint16_t* gB0 = Bb + (size_t)(w * 32 + srow) * 1024 + scol;
  const uint16_t* gB1 = gB0 + 16 * 1024;

  int woff = w * 1024;   // wave's 32-row block within a buffer (elems)

  auto STAGE = [&](uint16_t* dA, uint16_t* dB) {
    gload_lds16(gA0, dA + woff);
    gload_lds16(gA1, dA + woff + 512);
    gload_lds16(gB0, dB + woff);
    gload_lds16(gB1, dB + woff + 512);
    gA0 += 32; gA1 += 32; gB0 += 32; gB1 += 32;
  };

  // p0 = read this step (staged 2 steps ago), p1 = read next step,
  // p2 = stage target this step (was read one step ago).
  uint16_t* pA0 = As[0]; uint16_t* pA1 = As[1]; uint16_t* pA2 = As[2];
  uint16_t* pB0 = Bs[0]; uint16_t* pB1 = Bs[1]; uint16_t* pB2 = Bs[2];

  f32x4 acc[4][4] = {};

  STAGE(pA0, pB0);   // k-step 0
  STAGE(pA1, pB1);   // k-step 1

  for (int it = 0; it < 32; ++it) {
    if (it < 31) asm volatile("s_waitcnt vmcnt(4)" ::: "memory");  // own step-it loads landed
    else         asm volatile("s_waitcnt vmcnt(0)" ::: "memory");
    __builtin_amdgcn_s_barrier();            // ALL waves' step-it data landed
    if (it < 30) STAGE(pA2, pB2);            // k-step it+2 (buffer read at it-1)
    __builtin_amdgcn_sched_barrier(0);       // pin ds_reads below barrier/stage

    bf16x8 af[4], bfr[4];
#pragma unroll
    for (int i = 0; i < 4; i++)
      af[i] = *(const bf16x8*)&pA0[(wm * 64 + i * 16 + lm) * 32 + quad * 8];
#pragma unroll
    for (int j = 0; j < 4; j++)
      bfr[j] = *(const bf16x8*)&pB0[(wn * 64 + j * 16 + lm) * 32 + quad * 8];
#pragma unroll
    for (int i = 0; i < 4; i++)
#pragma unroll
      for (int j = 0; j < 4; j++)
        acc[i][j] = __builtin_amdgcn_mfma_f32_16x16x32_bf16(af[i], bfr[j], acc[i][j], 0, 0, 0);

    // rotate: new rd <- p1, new next <- p2 (staged now, read at it+2),
    // new stage target <- p0 (just read).
    uint16_t* tA = pA0; pA0 = pA1; pA1 = pA2; pA2 = tA;
    uint16_t* tB = pB0; pB0 = pB1; pB1 = pB2; pB2 = tB;
  }

  int rowb = tm * 128 + wm * 64;
  int colb = tn * 128 + wn * 64;
#pragma unroll
  for (int i = 0; i < 4; i++) {
#pragma unroll
    for (int j = 0; j < 4; j++) {
      int col = colb + j * 16 + lm;
#pragma unroll
      for (int r = 0; r < 4; r++) {
        int row = rowb + i * 16 + quad * 4 + r;
        float v = acc[i][j][r];
        if (mode == 2) {
          v += bias[row];
          int hh = row >> 6, hd = row & 63, b = col >> 11, s2 = col & 2047;
          ((uint16_t*)ga.C[2])[((size_t)((b * NH + hh) * 64 + hd) << 11) + s2] = f2bf(v);
        } else {
          v += bias[col];
          int b = row >> 11, s2 = row & 2047, hh = col >> 6, hd = col & 63;
          ((uint16_t*)ga.C[mode])[(((size_t)(b * NH + hh) * 2048 + s2) << 6) + hd] = f2bf(v);
        }
      }
    }
  }
}

// Out-projection: C[4096,1024] f32 = A[4096,1024]bf16 @ B[1024,1024]^T + bo.
// BM=64 x BN=128 -> 512 blocks = 2 blocks/CU. Depth-2 prefetch, same
// vmcnt-before-barrier ordering as gemm_bt.
__global__ __launch_bounds__(256) void gemm_out(const uint16_t* __restrict__ A,
                                                const uint16_t* __restrict__ Bm,
                                                const float* __restrict__ bias,
                                                float* __restrict__ C) {
  int bid = blockIdx.x;
  int tm = bid >> 3;     // 64 M-tiles
  int tn = bid & 7;      // 8 N-tiles

  __shared__ uint16_t As[3][64 * 32];    // 3 x 4 KB
  __shared__ uint16_t Bs[3][128 * 32];   // 3 x 8 KB

  int t = threadIdx.x;
  int lane = t & 63, w = t >> 6;
  int quad = lane >> 4, lm = lane & 15;
  int wm = w >> 1, wn = w & 1;

  const uint16_t* Ab = A + (size_t)tm * 64 * 1024;
  const uint16_t* Bb = Bm + (size_t)tn * 128 * 1024;

  int srow = lane >> 2;
  int scol = (lane & 3) * 8;
  const uint16_t* gA0 = Ab + (size_t)(w * 16 + srow) * 1024 + scol;   // A: 16 rows/wave
  const uint16_t* gB0 = Bb + (size_t)(w * 32 + srow) * 1024 + scol;   // B: 32 rows/wave
  const uint16_t* gB1 = gB0 + 16 * 1024;

  int woffA = w * 512;    // 16 rows * 32
  int woffB = w * 1024;   // 32 rows * 32

  auto STAGE = [&](uint16_t* dA, uint16_t* dB) {
    gload_lds16(gA0, dA + woffA);
    gload_lds16(gB0, dB + woffB);
    gload_lds16(gB1, dB + woffB + 512);
    gA0 += 32; gB0 += 32; gB1 += 32;
  };

  uint16_t* pA0 = As[0]; uint16_t* pA1 = As[1]; uint16_t* pA2 = As[2];
  uint16_t* pB0 = Bs[0]; uint16_t* pB1 = Bs[1]; uint16_t* pB2 = Bs[2];

  f32x4 acc[2][4] = {};

  STAGE(pA0, pB0);
  STAGE(pA1, pB1);

  for (int it = 0; it < 32; ++it) {
    if (it < 31) asm volatile("s_waitcnt vmcnt(3)" ::: "memory");
    else         asm volatile("s_waitcnt vmcnt(0)" ::: "memory");
    __builtin_amdgcn_s_barrier();
    if (it < 30) STAGE(pA2, pB2);
    __builtin_amdgcn_sched_barrier(0);

    bf16x8 af[2], bfr[4];
#pragma unroll
    for (int i = 0; i < 2; i++)
      af[i] = *(const bf16x8*)&pA0[(wm * 32 + i * 16 + lm) * 32 + quad * 8];
#pragma unroll
    for (int j = 0; j < 4; j++)
      bfr[j] = *(const bf16x8*)&pB0[(wn * 64 + j * 16 + lm) * 32 + quad * 8];
#pragma unroll
    for (int i = 0; i < 2; i++)
#pragma unroll
      for (int j = 0; j < 4; j++)
        acc[i][j] = __builtin_amdgcn_mfma_f32_16x16x32_bf16(af[i], bfr[j], acc[i][j], 0, 0, 0);

    uint16_t* tA = pA0; pA0 = pA1; pA1 = pA2; pA2 = tA;
    uint16_t* tB = pB0; pB0 = pB1; pB1 = pB2; pB2 = tB;
  }

  int rowb = tm * 64 + wm * 32;
  int colb = tn * 128 + wn * 64;
#pragma unroll
  for (int i = 0; i < 2; i++) {
#pragma unroll
    for (int j = 0; j < 4; j++) {
      int col = colb + j * 16 + lm;
      float bv = bias[col];
#pragma unroll
      for (int r = 0; r < 4; r++) {
        int row = rowb + i * 16 + quad * 4 + r;
        C[(size_t)row * 1024 + col] = acc[i][j][r] + bv;
      }
    }
  }
}

#define LDK 72  // 64x64 tile rows padded to 72 elems (144B, 16B-aligned)

// Flash attention. One WG = (head, 64-row q tile, batch). 4 waves, 256 thr.
// R5 structure (verified 105-107us). FROZEN -- R2/R6 restructures regressed.
__global__ __launch_bounds__(256) void attn(const uint16_t* __restrict__ qp,
                                            const uint16_t* __restrict__ kp,
                                            const uint16_t* __restrict__ vt,
                                            const uint16_t* __restrict__ cm,
                                            uint16_t* __restrict__ ao) {
  int h = blockIdx.x, qt = blockIdx.y, b = blockIdx.z;
  int t = threadIdx.x;
  int lane = t & 63, w = t >> 6;
  int quad = lane >> 4, c = lane & 15;

  __shared__ uint16_t Ks[64 * LDK];    // [k][hd]
  __shared__ uint16_t VTs[64 * LDK];   // [hd][k]
  __shared__ uint16_t Ps[64 * LDK];    // [q][k] (wave-private rows)

  size_t bh = (size_t)(b * NH + h);
  const uint16_t* Kb = kp + bh * (SEQ * 64);
  const uint16_t* Vb = vt + bh * (64 * SEQ);
  const uint16_t* CMb = cm + ((size_t)b * SEQ + qt * 64) * SEQ;

  int qrow = qt * 64 + w * 16 + c;
  const uint16_t* Qb = qp + bh * (SEQ * 64) + (size_t)qrow * 64;
  bf16x8 qf0 = *(const bf16x8*)(Qb + quad * 8);        // B-frag: Q[q][hd 0..32)
  bf16x8 qf1 = *(const bf16x8*)(Qb + 32 + quad * 8);   // hd 32..64

  f32x4 Oacc[4] = {};
  float m_run = NEG_BIG;
  float l_run = 0.0f;

  int krow = w * 8 + (lane >> 3);    // rows krow, krow+32
  int kc = (lane & 7) * 8;           // 16B chunk

  const uint16_t* pK0 = Kb + (size_t)krow * 64 + kc;
  const uint16_t* pK1 = pK0 + 32 * 64;
  const uint16_t* pV0 = Vb + (size_t)krow * SEQ + kc;
  const uint16_t* pV1 = pV0 + (size_t)32 * SEQ;
  const uint16_t* pCM = CMb + (size_t)(w * 16 + c) * SEQ + quad * 4;

  uint16_t* sK0 = &Ks[krow * LDK + kc];
  uint16_t* sK1 = sK0 + 32 * LDK;
  uint16_t* sV0 = &VTs[krow * LDK + kc];
  uint16_t* sV1 = sV0 + 32 * LDK;

  const uint16_t* rK = &Ks[c * LDK];
  const uint16_t* rV = &VTs[c * LDK];
  uint16_t* sP = &Ps[(w * 16 + c) * LDK];
  int qo = quad * 8;

  for (int kt = 0; kt < SEQ; kt += 64) {
    uint2 cm0 = *(const uint2*)(pCM);
    uint2 cm1 = *(const uint2*)(pCM + 16);
    uint2 cm2 = *(const uint2*)(pCM + 32);
    uint2 cm3 = *(const uint2*)(pCM + 48);
    uint4 k0  = *(const uint4*)(pK0);
    uint4 k1  = *(const uint4*)(pK1);
    uint4 v0g = *(const uint4*)(pV0);
    uint4 v1g = *(const uint4*)(pV1);
    pCM += 64; pK0 += 64 * 64; pK1 += 64 * 64; pV0 += 64; pV1 += 64;
    __syncthreads();                 // prev-tile LDS reads done
    *(uint4*)sK0 = k0;
    *(uint4*)sK1 = k1;
    *(uint4*)sV0 = v0g;
    *(uint4*)sV1 = v1g;
    __syncthreads();                 // tile staged

    f32x4 st[4];
    __builtin_amdgcn_s_setprio(1);
#pragma unroll
    for (int i = 0; i < 4; i++) {
      bf16x8 a0 = *(const bf16x8*)(rK + i * 16 * LDK + qo);
      bf16x8 a1 = *(const bf16x8*)(rK + i * 16 * LDK + 32 + qo);
      f32x4 z = {};
      z = __builtin_amdgcn_mfma_f32_16x16x32_bf16(a0, qf0, z, 0, 0, 0);
      st[i] = __builtin_amdgcn_mfma_f32_16x16x32_bf16(a1, qf1, z, 0, 0, 0);
    }
    __builtin_amdgcn_s_setprio(0);

    float p[16];
    float tmax = NEG_BIG;
    uint2 cmv[4] = {cm0, cm1, cm2, cm3};
#pragma unroll
    for (int i = 0; i < 4; i++) {
      uint32_t w0 = cmv[i].x, w1 = cmv[i].y;
      float cf[4];
      cf[0] = __builtin_bit_cast(float, w0 << 16);
      cf[1] = __builtin_bit_cast(float, w0 & 0xffff0000u);
      cf[2] = __builtin_bit_cast(float, w1 << 16);
      cf[3] = __builtin_bit_cast(float, w1 & 0xffff0000u);
#pragma unroll
      for (int r = 0; r < 4; r++) {
        float sv = st[i][r] * cf[r];
        sv = (cf[r] < 0.0f) ? NEG_BIG : sv;   // mask==0 -> -inf
        p[i * 4 + r] = sv;
      }
      tmax = fmaxf(tmax,
                   fmaxf(fmaxf(p[i * 4 + 0], p[i * 4 + 1]),
                         fmaxf(p[i * 4 + 2], p[i * 4 + 3])));
    }
    tmax = fmaxf(tmax, __shfl_xor(tmax, 16));
    tmax = fmaxf(tmax, __shfl_xor(tmax, 32));
    // T13 defer-max: skip rescale unless max grew by >8 (p bounded by 2^8)
    if (!__all(tmax <= m_run + 8.0f)) {
      float m_new = fmaxf(m_run, tmax);
      float alpha = exp2f(m_run - m_new);
      m_run = m_new;
      l_run *= alpha;
#pragma unroll
      for (int i = 0; i < 4; i++) Oacc[i] *= alpha;
    }
    float ls = 0.0f;
#pragma unroll
    for (int z2 = 0; z2 < 16; z2++) {
      p[z2] = exp2f(p[z2] - m_run);
      ls += p[z2];
    }
    l_run += ls;

#pragma unroll
    for (int i = 0; i < 4; i++) {
      uint2 pkd;
      pkd.x = cvtpk_bf16(p[i * 4 + 0], p[i * 4 + 1]);
      pkd.y = cvtpk_bf16(p[i * 4 + 2], p[i * 4 + 3]);
      *(uint2*)(sP + i * 16 + quad * 4) = pkd;
    }
    // P rows are wave-private: wave-local DS drain instead of __syncthreads
    asm volatile("s_waitcnt lgkmcnt(0)" ::: "memory");
    __builtin_amdgcn_sched_barrier(0);

    bf16x8 pf0 = *(const bf16x8*)(sP + qo);
    bf16x8 pf1 = *(const bf16x8*)(sP + 32 + qo);
    __builtin_amdgcn_s_setprio(1);
#pragma unroll
    for (int i = 0; i < 4; i++) {
      bf16x8 v0 = *(const bf16x8*)(rV + i * 16 * LDK + qo);
      bf16x8 v1 = *(const bf16x8*)(rV + i * 16 * LDK + 32 + qo);
      Oacc[i] = __builtin_amdgcn_mfma_f32_16x16x32_bf16(v0, pf0, Oacc[i], 0, 0, 0);
      Oacc[i] = __builtin_amdgcn_mfma_f32_16x16x32_bf16(v1, pf1, Oacc[i], 0, 0, 0);
    }
    __builtin_amdgcn_s_setprio(0);
  }

  float lf = l_run + __shfl_xor(l_run, 16);
  lf = lf + __shfl_xor(lf, 32);
  float inv = 1.0f / lf;
  uint16_t* Ob = ao + ((size_t)(b * SEQ) + qt * 64 + w * 16 + c) * HDIM + h * 64;
#pragma unroll
  for (int i = 0; i < 4; i++) {
    uint2 ov;
    ov.x = cvtpk_bf16(Oacc[i][0] * inv, Oacc[i][1] * inv);
    ov.y = cvtpk_bf16(Oacc[i][2] * inv, Oacc[i][3] * inv);
    *(uint2*)(Ob + i * 16 + quad * 4) = ov;
  }
}

extern "C" void kernel_launch(void* const* d_in, const int* in_sizes, int n_in,
                              void* d_out, int out_size, void* d_ws, size_t ws_size,
                              hipStream_t stream) {
  (void)in_sizes; (void)n_in; (void)out_size; (void)ws_size;
  const float* query = (const float*)d_in[0];
  const float* key   = (const float*)d_in[1];
  const float* value = (const float*)d_in[2];
  const int*   mask  = (const int*)d_in[3];
  const float* smask = (const float*)d_in[4];
  const float* Wq = (const float*)d_in[5];
  const float* bq = (const float*)d_in[6];
  const float* Wk = (const float*)d_in[7];
  const float* bk = (const float*)d_in[8];
  const float* Wv = (const float*)d_in[9];
  const float* bv = (const float*)d_in[10];
  const float* Wo = (const float*)d_in[11];
  const float* bo = (const float*)d_in[12];

  char* p = (char*)d_ws;
  uint16_t* xq  = (uint16_t*)p; p += (size_t)2 * SEQ * HDIM * 2;       // 8 MB
  uint16_t* xk  = (uint16_t*)p; p += (size_t)2 * SEQ * HDIM * 2;       // 8 MB
  uint16_t* xv  = (uint16_t*)p; p += (size_t)2 * SEQ * HDIM * 2;       // 8 MB
  uint16_t* wqb = (uint16_t*)p; p += (size_t)HDIM * HDIM * 2;          // 2 MB
  uint16_t* wkb = (uint16_t*)p; p += (size_t)HDIM * HDIM * 2;          // 2 MB
  uint16_t* wvb = (uint16_t*)p; p += (size_t)HDIM * HDIM * 2;          // 2 MB
  uint16_t* wob = (uint16_t*)p; p += (size_t)HDIM * HDIM * 2;          // 2 MB
  uint16_t* qp  = (uint16_t*)p; p += (size_t)2 * NH * SEQ * 64 * 2;    // 8 MB
  uint16_t* kpp = (uint16_t*)p; p += (size_t)2 * NH * SEQ * 64 * 2;    // 8 MB
  uint16_t* vtp = (uint16_t*)p; p += (size_t)2 * NH * SEQ * 64 * 2;    // 8 MB
  uint16_t* cmw = (uint16_t*)p; p += (size_t)2 * SEQ * SEQ * 2;        // 16 MB
  uint16_t* aob = (uint16_t*)p; p += (size_t)2 * SEQ * HDIM * 2;       // 8 MB

  PrepArgs pa;
  pa.src[0] = query; pa.dst[0] = xq;
  pa.src[1] = key;   pa.dst[1] = xk;
  pa.src[2] = value; pa.dst[2] = xv;
  pa.src[3] = Wq;    pa.dst[3] = wqb;
  pa.src[4] = Wk;    pa.dst[4] = wkb;
  pa.src[5] = Wv;    pa.dst[5] = wvb;
  pa.src[6] = Wo;    pa.dst[6] = wob;
  pa.mask = (const int4*)mask;
  pa.sm   = (const float4*)smask;
  pa.cmw  = (uint4*)cmw;
  prep<<<12288, 256, 0, stream>>>(pa);

  GemmArgs ga;
  ga.A[0] = xq;  ga.B[0] = wqb; ga.bias[0] = bq; ga.C[0] = qp;
  ga.A[1] = xk;  ga.B[1] = wkb; ga.bias[1] = bk; ga.C[1] = kpp;
  ga.A[2] = wvb; ga.B[2] = xv;  ga.bias[2] = bv; ga.C[2] = vtp;
  ga.A[3] = aob; ga.B[3] = wob; ga.bias[3] = bo; ga.C[3] = d_out;

  gemm_bt<<<dim3(256, 3), 256, 0, stream>>>(ga, 0);                // fused QKV
  attn<<<dim3(NH, SEQ / 64, 2), 256, 0, stream>>>(qp, kpp, vtp, cmw, aob);
  gemm_out<<<512, 256, 0, stream>>>(aob, wob, bo, (float*)d_out);  // output proj
}